// Round 12
// baseline (106.651 us; speedup 1.0000x reference)
//
#include <hip/hip_runtime.h>

// VQ color lookup, round 22: R21 resubmit -- pragma scoping fix only.
// R21 failed to compile: '#pragma clang fp contract(off)' must open a
// compound statement; in the resolve loop it followed a declaration. Fixed
// by wrapping the score block in braces. Everything else identical to R21:
// 8-wave 512-thread blocks (waves/SIMD back to 8), 8-entry super-groups
// (4 pairs = 2 x16 loads per fence; partial-min accumulation; 1 cmp/
// cndmask per 8 entries). Numerics bitwise R20: same quad_dist_s blob,
// exact fminf tree, strict-< at super/wave/combine levels, in-order
// resolve scan of the winning 8 => numpy first-index preserved.

#define KPAL 512
#define HW   65536            // 256*256
#define CHW  (3 * HW)
#define NPIX (8 * HW)         // 524288 pixels
#define NELEM (NPIX * 3)      // 1572864 output color elements
#define PPT   8               // pixels per thread (64 lanes * 8 = 512 px/block)
#define BLKPX (64 * PPT)      // 512
#define NWAVE 8               // 512-thread blocks
#define PAIRS_PER_WAVE (KPAL / 2 / NWAVE)     // 32 pairs = 64 entries
#define SUPERS_PER_WAVE (PAIRS_PER_WAVE / 4)  // 8 (8 entries each)

typedef float f2   __attribute__((ext_vector_type(2)));
typedef float f16v __attribute__((ext_vector_type(16)));

struct __align__(32) Pair {   // palette entries 2j (lo half) and 2j+1 (hi)
    f2 x, y, z, w;            // x,y,z = NEGATED color; w = 0.5 * ||t||^2
};

__device__ Pair g_pairs[KPAL / 2];          // 8 KB static device memory

// Pack the negated pair table; zero the loss accumulator.
__global__ void prep_kernel(const float* __restrict__ table,
                            float* __restrict__ loss)
{
    const int j = threadIdx.x;            // 0..255
    if (j == 0) *loss = 0.0f;
    const float a0 = table[6 * j + 0], a1 = table[6 * j + 1], a2 = table[6 * j + 2];
    const float b0 = table[6 * j + 3], b1 = table[6 * j + 4], b2 = table[6 * j + 5];
    float aw, bw;
    {
#pragma clang fp contract(off)
        aw = a0 * a0 + a1 * a1 + a2 * a2;
        bw = b0 * b0 + b1 * b1 + b2 * b2;
    }
    Pair p;
    p.x = (f2){-a0, -b0};
    p.y = (f2){-a1, -b1};
    p.z = (f2){-a2, -b2};
    p.w = (f2){0.5f * aw, 0.5f * bw};     // exact
    g_pairs[j] = p;
}

// 4 pixels x 1 palette pair (R13-exact numerics):
//   d = fma(nz, z2, fma(ny, z1, fma(nx, z0, hz))) + cw
// nx,ny,nz,cw are SGPR pairs (one per instr -> constant-bus legal).
// ZA=(z0,z1), ZB=(z2,hz); op_sel broadcasts the pixel component and hz.
static __device__ __forceinline__ void quad_dist_s(
    f2 nx, f2 ny, f2 nz, f2 cw,
    f2 A0, f2 B0, f2 A1, f2 B1, f2 A2, f2 B2, f2 A3, f2 B3,
    f2& r0, f2& r1, f2& r2, f2& r3)
{
    f2 d0, d1, d2, d3;
    asm("v_pk_fma_f32 %[d0], %[nx], %[A0], %[B0] op_sel:[0,0,1] op_sel_hi:[1,0,1]\n\t"
        "v_pk_fma_f32 %[d1], %[nx], %[A1], %[B1] op_sel:[0,0,1] op_sel_hi:[1,0,1]\n\t"
        "v_pk_fma_f32 %[d2], %[nx], %[A2], %[B2] op_sel:[0,0,1] op_sel_hi:[1,0,1]\n\t"
        "v_pk_fma_f32 %[d3], %[nx], %[A3], %[B3] op_sel:[0,0,1] op_sel_hi:[1,0,1]\n\t"
        "v_pk_fma_f32 %[d0], %[ny], %[A0], %[d0] op_sel:[0,1,0] op_sel_hi:[1,1,1]\n\t"
        "v_pk_fma_f32 %[d1], %[ny], %[A1], %[d1] op_sel:[0,1,0] op_sel_hi:[1,1,1]\n\t"
        "v_pk_fma_f32 %[d2], %[ny], %[A2], %[d2] op_sel:[0,1,0] op_sel_hi:[1,1,1]\n\t"
        "v_pk_fma_f32 %[d3], %[ny], %[A3], %[d3] op_sel:[0,1,0] op_sel_hi:[1,1,1]\n\t"
        "v_pk_fma_f32 %[d0], %[nz], %[B0], %[d0] op_sel:[0,0,0] op_sel_hi:[1,0,1]\n\t"
        "v_pk_fma_f32 %[d1], %[nz], %[B1], %[d1] op_sel:[0,0,0] op_sel_hi:[1,0,1]\n\t"
        "v_pk_fma_f32 %[d2], %[nz], %[B2], %[d2] op_sel:[0,0,0] op_sel_hi:[1,0,1]\n\t"
        "v_pk_fma_f32 %[d3], %[nz], %[B3], %[d3] op_sel:[0,0,0] op_sel_hi:[1,0,1]\n\t"
        "v_pk_add_f32 %[d0], %[d0], %[cw]\n\t"
        "v_pk_add_f32 %[d1], %[d1], %[cw]\n\t"
        "v_pk_add_f32 %[d2], %[d2], %[cw]\n\t"
        "v_pk_add_f32 %[d3], %[d3], %[cw]"
        : [d0] "=&v"(d0), [d1] "=&v"(d1), [d2] "=&v"(d2), [d3] "=&v"(d3)
        : [A0] "v"(A0), [B0] "v"(B0), [A1] "v"(A1), [B1] "v"(B1),
          [A2] "v"(A2), [B2] "v"(B2), [A3] "v"(A3), [B3] "v"(B3),
          [nx] "s"(nx), [ny] "s"(ny), [nz] "s"(nz), [cw] "s"(cw));
    r0 = d0; r1 = d1; r2 = d2; r3 = d3;
}

// One s_load_dwordx16 (two Pairs) into an SGPR 16-tuple.
#define SLOAD2(dst, off) \
    asm volatile("s_load_dwordx16 %0, %1, %2" : "=s"(dst) : "s"(pairs), "s"(off))
// Drain SMEM; tie both waited buffers so extraction can't hoist past it.
#define SFENCE2(d1, d2) \
    asm volatile("s_waitcnt lgkmcnt(0)" : "+s"(d1), "+s"(d2))

__global__ __launch_bounds__(512, 4)
void vq_kernel(const float* __restrict__ z,
               const float* __restrict__ table,
               float* __restrict__ out,
               float* __restrict__ loss)
{
    __shared__ float cb_best[NWAVE][BLKPX]; // 16 KB
    __shared__ int   cb_bi[NWAVE][BLKPX];   // 16 KB
    __shared__ float wsum[NWAVE];
    const Pair* __restrict__ pairs = g_pairs;
    const int t = threadIdx.x;                // 0..511
    const int w = t >> 6, lane = t & 63;      // 8 waves
    const int wu = __builtin_amdgcn_readfirstlane(w);   // wave-uniform SGPR

    // Block covers 512 consecutive pixels; all 8 waves process the same px.
    const int blockbase = blockIdx.x * BLKPX;
    const int b  = blockbase >> 16;           // blocks never straddle batch
    const int p0 = blockbase & (HW - 1);
    const int base0 = b * CHW + p0 + lane;    // pixel i at base0 + 64*i

    f2 ZA[PPT], ZB[PPT];                      // (z0,z1), (z2, 0.5*||z||^2)
#pragma unroll
    for (int i = 0; i < PPT; ++i) {
        const int base = base0 + 64 * i;
        const float z0 = z[base];
        const float z1 = z[base + HW];
        const float z2 = z[base + 2 * HW];
        float zs;
        {
#pragma clang fp contract(off)
            zs = z0 * z0 + z1 * z1 + z2 * z2;
        }
        ZA[i] = (f2){z0, z1};
        ZB[i] = (f2){z2, 0.5f * zs};          // exact halve
    }

    float best[PPT];
    int   bg[PPT];                            // global SUPER-group index (8 entries)
#pragma unroll
    for (int i = 0; i < PPT; ++i) { best[i] = 3.4e38f; bg[i] = wu * SUPERS_PER_WAVE; }

    // Wave w scans its palette eighth (64 entries = 32 pairs = 8 supers).
    const unsigned wbase = (unsigned)(wu * PAIRS_PER_WAVE) * 32u;

    // One PAIR_MIN: 2 entries x 8 px -> fold into running m via min3 (exact).
#define PAIR_MIN(V, H, MARR, FIRST)                                          \
    do {                                                                     \
        const f2 nx = (f2){(V)[(H) + 0], (V)[(H) + 1]};                      \
        const f2 ny = (f2){(V)[(H) + 2], (V)[(H) + 3]};                      \
        const f2 nz = (f2){(V)[(H) + 4], (V)[(H) + 5]};                      \
        const f2 cw = (f2){(V)[(H) + 6], (V)[(H) + 7]};                      \
        f2 r[PPT];                                                           \
        quad_dist_s(nx, ny, nz, cw,                                          \
                    ZA[0], ZB[0], ZA[1], ZB[1], ZA[2], ZB[2], ZA[3], ZB[3],  \
                    r[0], r[1], r[2], r[3]);                                 \
        quad_dist_s(nx, ny, nz, cw,                                          \
                    ZA[4], ZB[4], ZA[5], ZB[5], ZA[6], ZB[6], ZA[7], ZB[7],  \
                    r[4], r[5], r[6], r[7]);                                 \
        _Pragma("unroll")                                                    \
        for (int i = 0; i < PPT; ++i) {                                      \
            const float seed = (FIRST) ? best[i] : MARR[i];                  \
            MARR[i] = fminf(fminf(seed, r[i].x), r[i].y);                    \
        }                                                                    \
    } while (0)

    // One super-group = 8 entries (pairs 4g..4g+3 = buffers V1,V2).
#define SUPER_STEP(V1, V2, G)                                                \
    do {                                                                     \
        float m[PPT];                                                        \
        PAIR_MIN(V1, 0, m, true);                                            \
        PAIR_MIN(V1, 8, m, false);                                           \
        PAIR_MIN(V2, 0, m, false);                                           \
        PAIR_MIN(V2, 8, m, false);                                           \
        const int gv = (G);                                                  \
        _Pragma("unroll")                                                    \
        for (int i = 0; i < PPT; ++i) {                                      \
            const bool imp = m[i] < best[i];                                 \
            bg[i] = imp ? gv : bg[i];                                        \
            best[i] = m[i];                                                  \
        }                                                                    \
    } while (0)

    {
        f16v A1, A2, B1, B2;
        SLOAD2(A1, wbase);                                // super 0
        SLOAD2(A2, wbase + 64u);
#pragma unroll 1
        for (int s = 0; s < SUPERS_PER_WAVE; s += 2) {
            const int g0 = wu * SUPERS_PER_WAVE + s;
            const unsigned ob = wbase + (unsigned)(s + 1) * 128u;
            SFENCE2(A1, A2);                              // only A1,A2 outstanding
            SLOAD2(B1, ob);                               // hide under super A
            SLOAD2(B2, ob + 64u);
            SUPER_STEP(A1, A2, g0);
            SFENCE2(B1, B2);                              // only B1,B2 outstanding
            if (s + 2 < SUPERS_PER_WAVE) {
                const unsigned oa = wbase + (unsigned)(s + 2) * 128u;
                SLOAD2(A1, oa);                           // hide under super B
                SLOAD2(A2, oa + 64u);
            }
            SUPER_STEP(B1, B2, g0 + 1);
        }
    }
#undef SUPER_STEP
#undef PAIR_MIN

    // Resolve the winning entry within the winning 8-entry super-group:
    // recompute all 8 scores with scalar chains that replicate the pk lanes
    // BITWISE (v_pk_fma lane == fmaf, v_pk_add lane == scalar add); first
    // == best -> numpy first-index within the group.
#pragma unroll
    for (int i = 0; i < PPT; ++i) {
        const int g = bg[i];
        float sc[8];
#pragma unroll
        for (int q = 0; q < 4; ++q) {
            const Pair c = pairs[4 * g + q];  // per-lane gather, L1-hit (8 KB)
            {
#pragma clang fp contract(off)
                float m;
                m = fmaf(c.x.x, ZA[i].x, ZB[i].y);
                m = fmaf(c.y.x, ZA[i].y, m);
                m = fmaf(c.z.x, ZB[i].x, m);
                sc[2 * q] = m + c.w.x;
                m = fmaf(c.x.y, ZA[i].x, ZB[i].y);
                m = fmaf(c.y.y, ZA[i].y, m);
                m = fmaf(c.z.y, ZB[i].x, m);
                sc[2 * q + 1] = m + c.w.y;
            }
        }
        const float bb = best[i];
        const int m8 = (sc[0] == bb) ? 0 : (sc[1] == bb) ? 1
                     : (sc[2] == bb) ? 2 : (sc[3] == bb) ? 3
                     : (sc[4] == bb) ? 4 : (sc[5] == bb) ? 5
                     : (sc[6] == bb) ? 6 : 7;
        cb_best[w][lane + 64 * i] = bb;
        cb_bi[w][lane + 64 * i]   = 8 * g + m8;
    }
    __syncthreads();

    // Combine eighths (ordered strict < => numpy first-index), write, loss.
    // px p = t was scanned by THIS thread at slot i == w: reuse regs.
    f2 zA = ZA[0], zB = ZB[0];
    if (w == 1)      { zA = ZA[1]; zB = ZB[1]; }
    else if (w == 2) { zA = ZA[2]; zB = ZB[2]; }
    else if (w == 3) { zA = ZA[3]; zB = ZB[3]; }
    else if (w == 4) { zA = ZA[4]; zB = ZB[4]; }
    else if (w == 5) { zA = ZA[5]; zB = ZB[5]; }
    else if (w == 6) { zA = ZA[6]; zB = ZB[6]; }
    else if (w == 7) { zA = ZA[7]; zB = ZB[7]; }

    float lsum = 0.0f;
    {
        const int p = t;                      // 0..511 within block
        float bb = cb_best[0][p];
        int   kk = cb_bi[0][p];
#pragma unroll
        for (int ww = 1; ww < NWAVE; ++ww) {
            const float d  = cb_best[ww][p];
            const int   k2 = cb_bi[ww][p];
            if (d < bb) { bb = d; kk = k2; }
        }
        const int base = b * CHW + p0 + p;
        const float c0 = table[3 * kk + 0];
        const float c1 = table[3 * kk + 1];
        const float c2 = table[3 * kk + 2];
        out[base]          = c0;
        out[base + HW]     = c1;
        out[base + 2 * HW] = c2;
        const float e0 = c0 - zA.x, e1 = c1 - zA.y, e2 = c2 - zB.x;
        lsum = e0 * e0 + e1 * e1 + e2 * e2;
    }

    for (int off = 32; off > 0; off >>= 1)
        lsum += __shfl_down(lsum, off);

    if ((t & 63) == 0) wsum[w] = lsum;
    __syncthreads();
    if (t == 0) {
        float s = 0.0f;
#pragma unroll
        for (int ww = 0; ww < NWAVE; ++ww) s += wsum[ww];
        atomicAdd(loss, s * (11.0f / (float)NELEM));
    }
}

extern "C" void kernel_launch(void* const* d_in, const int* in_sizes, int n_in,
                              void* d_out, int out_size, void* d_ws, size_t ws_size,
                              hipStream_t stream)
{
    const float* z     = (const float*)d_in[0];
    const float* table = (const float*)d_in[1];
    float* out  = (float*)d_out;
    float* loss = out + NELEM;

    prep_kernel<<<1, 256, 0, stream>>>(table, loss);
    vq_kernel<<<NPIX / BLKPX, 512, 0, stream>>>(z, table, out, loss);
}

// Round 13
// 93.534 us; speedup vs baseline: 1.1402x; 1.1402x over previous
//
#include <hip/hip_runtime.h>

// VQ color lookup, round 23: R20 chassis + R22 super-group selects.
// R22 post-mortem: super-groups cut busy to 25us (best ever) but the
// 512-thread/33KB-LDS chassis tanked residency (Occ 37% = ~12 waves/CU)
// -> dur 53us. Right optimization, wrong chassis. This round: R20's
// proven chassis (256 thr, NWAVE=4, PPT=8, 16.6KB LDS, 4 blk/CU, grid
// 1024) + super-groups of 4 pairs (8 entries) matching R20's existing
// fence interval. Selects per 4 pairs per px: 8 ops -> 6 (partial-min
// accumulation + one cmp/cndmask per super). Resolve widens to 8 entries.
// Census: pk floor 27.3us + selects ~5us -> wall ~34-36us; R20 was 38.8.
// Numerics bitwise R20/R22 (both absmax 0.0): same quad_dist_s blob,
// exact fminf tree, strict-< at super/wave/combine, in-order resolve.

#define KPAL 512
#define HW   65536            // 256*256
#define CHW  (3 * HW)
#define NPIX (8 * HW)         // 524288 pixels
#define NELEM (NPIX * 3)      // 1572864 output color elements
#define PPT   8               // pixels per thread (64 lanes * 8 = 512 px/block)
#define BLKPX (64 * PPT)      // 512
#define NWAVE 4
#define PAIRS_PER_WAVE (KPAL / 2 / NWAVE)     // 64 pairs = 128 entries
#define SUPERS_PER_WAVE (PAIRS_PER_WAVE / 4)  // 16 (8 entries each)

typedef float f2   __attribute__((ext_vector_type(2)));
typedef float f16v __attribute__((ext_vector_type(16)));

struct __align__(32) Pair {   // palette entries 2j (lo half) and 2j+1 (hi)
    f2 x, y, z, w;            // x,y,z = NEGATED color; w = 0.5 * ||t||^2
};

__device__ Pair g_pairs[KPAL / 2];          // 8 KB static device memory

// Pack the negated pair table; zero the loss accumulator.
__global__ void prep_kernel(const float* __restrict__ table,
                            float* __restrict__ loss)
{
    const int j = threadIdx.x;            // 0..255
    if (j == 0) *loss = 0.0f;
    const float a0 = table[6 * j + 0], a1 = table[6 * j + 1], a2 = table[6 * j + 2];
    const float b0 = table[6 * j + 3], b1 = table[6 * j + 4], b2 = table[6 * j + 5];
    float aw, bw;
    {
#pragma clang fp contract(off)
        aw = a0 * a0 + a1 * a1 + a2 * a2;
        bw = b0 * b0 + b1 * b1 + b2 * b2;
    }
    Pair p;
    p.x = (f2){-a0, -b0};
    p.y = (f2){-a1, -b1};
    p.z = (f2){-a2, -b2};
    p.w = (f2){0.5f * aw, 0.5f * bw};     // exact
    g_pairs[j] = p;
}

// 4 pixels x 1 palette pair (R13-exact numerics):
//   d = fma(nz, z2, fma(ny, z1, fma(nx, z0, hz))) + cw
// nx,ny,nz,cw are SGPR pairs (one per instr -> constant-bus legal).
// ZA=(z0,z1), ZB=(z2,hz); op_sel broadcasts the pixel component and hz.
static __device__ __forceinline__ void quad_dist_s(
    f2 nx, f2 ny, f2 nz, f2 cw,
    f2 A0, f2 B0, f2 A1, f2 B1, f2 A2, f2 B2, f2 A3, f2 B3,
    f2& r0, f2& r1, f2& r2, f2& r3)
{
    f2 d0, d1, d2, d3;
    asm("v_pk_fma_f32 %[d0], %[nx], %[A0], %[B0] op_sel:[0,0,1] op_sel_hi:[1,0,1]\n\t"
        "v_pk_fma_f32 %[d1], %[nx], %[A1], %[B1] op_sel:[0,0,1] op_sel_hi:[1,0,1]\n\t"
        "v_pk_fma_f32 %[d2], %[nx], %[A2], %[B2] op_sel:[0,0,1] op_sel_hi:[1,0,1]\n\t"
        "v_pk_fma_f32 %[d3], %[nx], %[A3], %[B3] op_sel:[0,0,1] op_sel_hi:[1,0,1]\n\t"
        "v_pk_fma_f32 %[d0], %[ny], %[A0], %[d0] op_sel:[0,1,0] op_sel_hi:[1,1,1]\n\t"
        "v_pk_fma_f32 %[d1], %[ny], %[A1], %[d1] op_sel:[0,1,0] op_sel_hi:[1,1,1]\n\t"
        "v_pk_fma_f32 %[d2], %[ny], %[A2], %[d2] op_sel:[0,1,0] op_sel_hi:[1,1,1]\n\t"
        "v_pk_fma_f32 %[d3], %[ny], %[A3], %[d3] op_sel:[0,1,0] op_sel_hi:[1,1,1]\n\t"
        "v_pk_fma_f32 %[d0], %[nz], %[B0], %[d0] op_sel:[0,0,0] op_sel_hi:[1,0,1]\n\t"
        "v_pk_fma_f32 %[d1], %[nz], %[B1], %[d1] op_sel:[0,0,0] op_sel_hi:[1,0,1]\n\t"
        "v_pk_fma_f32 %[d2], %[nz], %[B2], %[d2] op_sel:[0,0,0] op_sel_hi:[1,0,1]\n\t"
        "v_pk_fma_f32 %[d3], %[nz], %[B3], %[d3] op_sel:[0,0,0] op_sel_hi:[1,0,1]\n\t"
        "v_pk_add_f32 %[d0], %[d0], %[cw]\n\t"
        "v_pk_add_f32 %[d1], %[d1], %[cw]\n\t"
        "v_pk_add_f32 %[d2], %[d2], %[cw]\n\t"
        "v_pk_add_f32 %[d3], %[d3], %[cw]"
        : [d0] "=&v"(d0), [d1] "=&v"(d1), [d2] "=&v"(d2), [d3] "=&v"(d3)
        : [A0] "v"(A0), [B0] "v"(B0), [A1] "v"(A1), [B1] "v"(B1),
          [A2] "v"(A2), [B2] "v"(B2), [A3] "v"(A3), [B3] "v"(B3),
          [nx] "s"(nx), [ny] "s"(ny), [nz] "s"(nz), [cw] "s"(cw));
    r0 = d0; r1 = d1; r2 = d2; r3 = d3;
}

// One s_load_dwordx16 (two Pairs) into an SGPR 16-tuple.
#define SLOAD2(dst, off) \
    asm volatile("s_load_dwordx16 %0, %1, %2" : "=s"(dst) : "s"(pairs), "s"(off))
// Drain SMEM; tie both waited buffers so extraction can't hoist past it.
#define SFENCE2(d1, d2) \
    asm volatile("s_waitcnt lgkmcnt(0)" : "+s"(d1), "+s"(d2))

__global__ __launch_bounds__(256, 4)
void vq_kernel(const float* __restrict__ z,
               const float* __restrict__ table,
               float* __restrict__ out,
               float* __restrict__ loss)
{
    __shared__ float cb_best[NWAVE][BLKPX]; // 8 KB
    __shared__ int   cb_bi[NWAVE][BLKPX];   // 8 KB
    __shared__ float wsum[NWAVE];
    const Pair* __restrict__ pairs = g_pairs;
    const int t = threadIdx.x;
    const int w = t >> 6, lane = t & 63;
    const int wu = __builtin_amdgcn_readfirstlane(w);   // wave-uniform SGPR

    // Block covers 512 consecutive pixels; all 4 waves process the same px.
    const int blockbase = blockIdx.x * BLKPX;
    const int b  = blockbase >> 16;           // blocks never straddle batch
    const int p0 = blockbase & (HW - 1);
    const int base0 = b * CHW + p0 + lane;    // pixel i at base0 + 64*i

    f2 ZA[PPT], ZB[PPT];                      // (z0,z1), (z2, 0.5*||z||^2)
#pragma unroll
    for (int i = 0; i < PPT; ++i) {
        const int base = base0 + 64 * i;
        const float z0 = z[base];
        const float z1 = z[base + HW];
        const float z2 = z[base + 2 * HW];
        float zs;
        {
#pragma clang fp contract(off)
            zs = z0 * z0 + z1 * z1 + z2 * z2;
        }
        ZA[i] = (f2){z0, z1};
        ZB[i] = (f2){z2, 0.5f * zs};          // exact halve
    }

    float best[PPT];
    int   bg[PPT];                            // global SUPER-group index (8 entries)
#pragma unroll
    for (int i = 0; i < PPT; ++i) { best[i] = 3.4e38f; bg[i] = wu * SUPERS_PER_WAVE; }

    // Wave w scans its palette quarter (128 entries = 64 pairs = 16 supers).
    const unsigned wbase = (unsigned)(wu * PAIRS_PER_WAVE) * 32u;

    // One PAIR_MIN: 2 entries x 8 px -> fold into running m via min3 (exact).
#define PAIR_MIN(V, H, MARR, FIRST)                                          \
    do {                                                                     \
        const f2 nx = (f2){(V)[(H) + 0], (V)[(H) + 1]};                      \
        const f2 ny = (f2){(V)[(H) + 2], (V)[(H) + 3]};                      \
        const f2 nz = (f2){(V)[(H) + 4], (V)[(H) + 5]};                      \
        const f2 cw = (f2){(V)[(H) + 6], (V)[(H) + 7]};                      \
        f2 r[PPT];                                                           \
        quad_dist_s(nx, ny, nz, cw,                                          \
                    ZA[0], ZB[0], ZA[1], ZB[1], ZA[2], ZB[2], ZA[3], ZB[3],  \
                    r[0], r[1], r[2], r[3]);                                 \
        quad_dist_s(nx, ny, nz, cw,                                          \
                    ZA[4], ZB[4], ZA[5], ZB[5], ZA[6], ZB[6], ZA[7], ZB[7],  \
                    r[4], r[5], r[6], r[7]);                                 \
        _Pragma("unroll")                                                    \
        for (int i = 0; i < PPT; ++i) {                                      \
            const float seed = (FIRST) ? best[i] : MARR[i];                  \
            MARR[i] = fminf(fminf(seed, r[i].x), r[i].y);                    \
        }                                                                    \
    } while (0)

    // One super-group = 8 entries (pairs 4s..4s+3 = buffers V1,V2).
#define SUPER_STEP(V1, V2, G)                                                \
    do {                                                                     \
        float m[PPT];                                                        \
        PAIR_MIN(V1, 0, m, true);                                            \
        PAIR_MIN(V1, 8, m, false);                                           \
        PAIR_MIN(V2, 0, m, false);                                           \
        PAIR_MIN(V2, 8, m, false);                                           \
        const int gv = (G);                                                  \
        _Pragma("unroll")                                                    \
        for (int i = 0; i < PPT; ++i) {                                      \
            const bool imp = m[i] < best[i];                                 \
            bg[i] = imp ? gv : bg[i];                                        \
            best[i] = m[i];                                                  \
        }                                                                    \
    } while (0)

    {
        f16v A1, A2, B1, B2;
        SLOAD2(A1, wbase);                                // super 0
        SLOAD2(A2, wbase + 64u);
#pragma unroll 1
        for (int s = 0; s < SUPERS_PER_WAVE; s += 2) {
            const int g0 = wu * SUPERS_PER_WAVE + s;
            const unsigned ob = wbase + (unsigned)(s + 1) * 128u;
            SFENCE2(A1, A2);                              // only A1,A2 outstanding
            SLOAD2(B1, ob);                               // hide under super A
            SLOAD2(B2, ob + 64u);
            SUPER_STEP(A1, A2, g0);
            SFENCE2(B1, B2);                              // only B1,B2 outstanding
            if (s + 2 < SUPERS_PER_WAVE) {
                const unsigned oa = wbase + (unsigned)(s + 2) * 128u;
                SLOAD2(A1, oa);                           // hide under super B
                SLOAD2(A2, oa + 64u);
            }
            SUPER_STEP(B1, B2, g0 + 1);
        }
    }
#undef SUPER_STEP
#undef PAIR_MIN

    // Resolve the winning entry within the winning 8-entry super-group:
    // recompute all 8 scores with scalar chains that replicate the pk lanes
    // BITWISE (v_pk_fma lane == fmaf, v_pk_add lane == scalar add); first
    // == best -> numpy first-index within the group.
#pragma unroll
    for (int i = 0; i < PPT; ++i) {
        const int g = bg[i];
        float sc[8];
#pragma unroll
        for (int q = 0; q < 4; ++q) {
            const Pair c = pairs[4 * g + q];  // per-lane gather, L1-hit (8 KB)
            {
#pragma clang fp contract(off)
                float m;
                m = fmaf(c.x.x, ZA[i].x, ZB[i].y);
                m = fmaf(c.y.x, ZA[i].y, m);
                m = fmaf(c.z.x, ZB[i].x, m);
                sc[2 * q] = m + c.w.x;
                m = fmaf(c.x.y, ZA[i].x, ZB[i].y);
                m = fmaf(c.y.y, ZA[i].y, m);
                m = fmaf(c.z.y, ZB[i].x, m);
                sc[2 * q + 1] = m + c.w.y;
            }
        }
        const float bb = best[i];
        const int m8 = (sc[0] == bb) ? 0 : (sc[1] == bb) ? 1
                     : (sc[2] == bb) ? 2 : (sc[3] == bb) ? 3
                     : (sc[4] == bb) ? 4 : (sc[5] == bb) ? 5
                     : (sc[6] == bb) ? 6 : 7;
        cb_best[w][lane + 64 * i] = bb;
        cb_bi[w][lane + 64 * i]   = 8 * g + m8;
    }
    __syncthreads();

    // Combine quarters (ordered strict < => numpy first-index), write, loss.
    // Thread t combines px t (= its slot w) and px t+256 (= its slot w+4):
    // reuse regs, no z re-read.
    float lsum = 0.0f;
#pragma unroll
    for (int half = 0; half < 2; ++half) {
        const int p = t + 256 * half;         // 0..511 within block
        const int slot = w + 4 * half;
        const f2 zA = ZA[slot], zB = ZB[slot];
        float bb = cb_best[0][p];
        int   kk = cb_bi[0][p];
#pragma unroll
        for (int ww = 1; ww < NWAVE; ++ww) {
            const float d  = cb_best[ww][p];
            const int   k2 = cb_bi[ww][p];
            if (d < bb) { bb = d; kk = k2; }
        }
        const int base = b * CHW + p0 + p;
        const float c0 = table[3 * kk + 0];
        const float c1 = table[3 * kk + 1];
        const float c2 = table[3 * kk + 2];
        out[base]          = c0;
        out[base + HW]     = c1;
        out[base + 2 * HW] = c2;
        const float e0 = c0 - zA.x, e1 = c1 - zA.y, e2 = c2 - zB.x;
        lsum += e0 * e0 + e1 * e1 + e2 * e2;
    }

    for (int off = 32; off > 0; off >>= 1)
        lsum += __shfl_down(lsum, off);

    if ((t & 63) == 0) wsum[w] = lsum;
    __syncthreads();
    if (t == 0) {
        const float s = wsum[0] + wsum[1] + wsum[2] + wsum[3];
        atomicAdd(loss, s * (11.0f / (float)NELEM));
    }
}

extern "C" void kernel_launch(void* const* d_in, const int* in_sizes, int n_in,
                              void* d_out, int out_size, void* d_ws, size_t ws_size,
                              hipStream_t stream)
{
    const float* z     = (const float*)d_in[0];
    const float* table = (const float*)d_in[1];
    float* out  = (float*)d_out;
    float* loss = out + NELEM;

    prep_kernel<<<1, 256, 0, stream>>>(table, loss);
    vq_kernel<<<NPIX / BLKPX, 256, 0, stream>>>(z, table, out, loss);
}

// Round 14
// 92.782 us; speedup vs baseline: 1.1495x; 1.0081x over previous
//
#include <hip/hip_runtime.h>

// VQ color lookup, round 24: restore R20 verbatim (session best, 91.8us).
// R23 post-mortem: super-groups on the R20 chassis = 93.5us (no gain);
// R16/R20/R22/R23 oscillate +-2% around the structural floor. Census:
// formula locked bitwise by R14's failure (numpy argmin has ulp-close
// ties); minimum work = 8.39M v_pk wave-insts; at measured VOP3P rate
// (~8cyc, R19 busy-census) = ~27us + ~5us selects -> vq wall 32-35us;
// best measured 38.8 (83-90% of census). Bench has ~53us fixed harness
// overhead -> remaining capturable <=4%; six targeted attempts failed to
// capture it. This resubmission locks in the best-known kernel.
// Structure: 256 thr, NWAVE=4, PPT=8 (512 px/block, grid 1024), pk score
// blob (R13-exact numerics), s_load_dwordx16 A/B/A2/B2 delivery with one
// full lgkmcnt(0) drain per 2 group-steps, exact fminf tree select at
// group level, bitwise scalar resolve, strict-< first-index combine.

#define KPAL 512
#define HW   65536            // 256*256
#define CHW  (3 * HW)
#define NPIX (8 * HW)         // 524288 pixels
#define NELEM (NPIX * 3)      // 1572864 output color elements
#define PPT   8               // pixels per thread (64 lanes * 8 = 512 px/block)
#define BLKPX (64 * PPT)      // 512
#define NWAVE 4
#define PAIRS_PER_WAVE (KPAL / 2 / NWAVE)   // 64
#define GROUPS_PER_WAVE (PAIRS_PER_WAVE / 2) // 32 (2 pairs = 4 entries each)

typedef float f2   __attribute__((ext_vector_type(2)));
typedef float f16v __attribute__((ext_vector_type(16)));

struct __align__(32) Pair {   // palette entries 2j (lo half) and 2j+1 (hi)
    f2 x, y, z, w;            // x,y,z = NEGATED color; w = 0.5 * ||t||^2
};

__device__ Pair g_pairs[KPAL / 2];          // 8 KB static device memory

// Pack the negated pair table; zero the loss accumulator.
__global__ void prep_kernel(const float* __restrict__ table,
                            float* __restrict__ loss)
{
    const int j = threadIdx.x;            // 0..255
    if (j == 0) *loss = 0.0f;
    const float a0 = table[6 * j + 0], a1 = table[6 * j + 1], a2 = table[6 * j + 2];
    const float b0 = table[6 * j + 3], b1 = table[6 * j + 4], b2 = table[6 * j + 5];
    float aw, bw;
    {
#pragma clang fp contract(off)
        aw = a0 * a0 + a1 * a1 + a2 * a2;
        bw = b0 * b0 + b1 * b1 + b2 * b2;
    }
    Pair p;
    p.x = (f2){-a0, -b0};
    p.y = (f2){-a1, -b1};
    p.z = (f2){-a2, -b2};
    p.w = (f2){0.5f * aw, 0.5f * bw};     // exact
    g_pairs[j] = p;
}

// 4 pixels x 1 palette pair (R13-exact numerics):
//   d = fma(nz, z2, fma(ny, z1, fma(nx, z0, hz))) + cw
// nx,ny,nz,cw are SGPR pairs (one per instr -> constant-bus legal).
// ZA=(z0,z1), ZB=(z2,hz); op_sel broadcasts the pixel component and hz.
static __device__ __forceinline__ void quad_dist_s(
    f2 nx, f2 ny, f2 nz, f2 cw,
    f2 A0, f2 B0, f2 A1, f2 B1, f2 A2, f2 B2, f2 A3, f2 B3,
    f2& r0, f2& r1, f2& r2, f2& r3)
{
    f2 d0, d1, d2, d3;
    asm("v_pk_fma_f32 %[d0], %[nx], %[A0], %[B0] op_sel:[0,0,1] op_sel_hi:[1,0,1]\n\t"
        "v_pk_fma_f32 %[d1], %[nx], %[A1], %[B1] op_sel:[0,0,1] op_sel_hi:[1,0,1]\n\t"
        "v_pk_fma_f32 %[d2], %[nx], %[A2], %[B2] op_sel:[0,0,1] op_sel_hi:[1,0,1]\n\t"
        "v_pk_fma_f32 %[d3], %[nx], %[A3], %[B3] op_sel:[0,0,1] op_sel_hi:[1,0,1]\n\t"
        "v_pk_fma_f32 %[d0], %[ny], %[A0], %[d0] op_sel:[0,1,0] op_sel_hi:[1,1,1]\n\t"
        "v_pk_fma_f32 %[d1], %[ny], %[A1], %[d1] op_sel:[0,1,0] op_sel_hi:[1,1,1]\n\t"
        "v_pk_fma_f32 %[d2], %[ny], %[A2], %[d2] op_sel:[0,1,0] op_sel_hi:[1,1,1]\n\t"
        "v_pk_fma_f32 %[d3], %[ny], %[A3], %[d3] op_sel:[0,1,0] op_sel_hi:[1,1,1]\n\t"
        "v_pk_fma_f32 %[d0], %[nz], %[B0], %[d0] op_sel:[0,0,0] op_sel_hi:[1,0,1]\n\t"
        "v_pk_fma_f32 %[d1], %[nz], %[B1], %[d1] op_sel:[0,0,0] op_sel_hi:[1,0,1]\n\t"
        "v_pk_fma_f32 %[d2], %[nz], %[B2], %[d2] op_sel:[0,0,0] op_sel_hi:[1,0,1]\n\t"
        "v_pk_fma_f32 %[d3], %[nz], %[B3], %[d3] op_sel:[0,0,0] op_sel_hi:[1,0,1]\n\t"
        "v_pk_add_f32 %[d0], %[d0], %[cw]\n\t"
        "v_pk_add_f32 %[d1], %[d1], %[cw]\n\t"
        "v_pk_add_f32 %[d2], %[d2], %[cw]\n\t"
        "v_pk_add_f32 %[d3], %[d3], %[cw]"
        : [d0] "=&v"(d0), [d1] "=&v"(d1), [d2] "=&v"(d2), [d3] "=&v"(d3)
        : [A0] "v"(A0), [B0] "v"(B0), [A1] "v"(A1), [B1] "v"(B1),
          [A2] "v"(A2), [B2] "v"(B2), [A3] "v"(A3), [B3] "v"(B3),
          [nx] "s"(nx), [ny] "s"(ny), [nz] "s"(nz), [cw] "s"(cw));
    r0 = d0; r1 = d1; r2 = d2; r3 = d3;
}

// One s_load_dwordx16 (two Pairs = one 4-entry group) into an SGPR 16-tuple.
#define SLOAD2(dst, off) \
    asm volatile("s_load_dwordx16 %0, %1, %2" : "=s"(dst) : "s"(pairs), "s"(off))
// Drain SMEM; tie both waited buffers so extraction can't hoist past it.
#define SFENCE2(d1, d2) \
    asm volatile("s_waitcnt lgkmcnt(0)" : "+s"(d1), "+s"(d2))

__global__ __launch_bounds__(256, 4)
void vq_kernel(const float* __restrict__ z,
               const float* __restrict__ table,
               float* __restrict__ out,
               float* __restrict__ loss)
{
    __shared__ float cb_best[NWAVE][BLKPX]; // 8 KB
    __shared__ int   cb_bi[NWAVE][BLKPX];   // 8 KB
    __shared__ float wsum[NWAVE];
    const Pair* __restrict__ pairs = g_pairs;
    const int t = threadIdx.x;
    const int w = t >> 6, lane = t & 63;
    const int wu = __builtin_amdgcn_readfirstlane(w);   // wave-uniform SGPR

    // Block covers 512 consecutive pixels; all 4 waves process the same px.
    const int blockbase = blockIdx.x * BLKPX;
    const int b  = blockbase >> 16;           // blocks never straddle batch
    const int p0 = blockbase & (HW - 1);
    const int base0 = b * CHW + p0 + lane;    // pixel i at base0 + 64*i

    f2 ZA[PPT], ZB[PPT];                      // (z0,z1), (z2, 0.5*||z||^2)
#pragma unroll
    for (int i = 0; i < PPT; ++i) {
        const int base = base0 + 64 * i;
        const float z0 = z[base];
        const float z1 = z[base + HW];
        const float z2 = z[base + 2 * HW];
        float zs;
        {
#pragma clang fp contract(off)
            zs = z0 * z0 + z1 * z1 + z2 * z2;
        }
        ZA[i] = (f2){z0, z1};
        ZB[i] = (f2){z2, 0.5f * zs};          // exact halve
    }

    float best[PPT];
    int   bg[PPT];                            // global GROUP index (4 entries)
#pragma unroll
    for (int i = 0; i < PPT; ++i) { best[i] = 3.4e38f; bg[i] = wu * GROUPS_PER_WAVE; }

    // Wave w scans its palette quarter; one x16 load = one 4-entry group.
    const unsigned wbase = (unsigned)(wu * PAIRS_PER_WAVE) * 32u;

    // One group = 2 pairs from one x16 buffer; 8 px via two 4-px blob calls
    // per pair. Tree select (exact): mn = min3(min3(best, ra.x, ra.y),
    // rb.x, rb.y); strict < keeps earlier group -> first-index at group level.
#define GROUP_STEP(V, G)                                                     \
    do {                                                                     \
        const f2 nx0 = (f2){(V)[0], (V)[1]};                                 \
        const f2 ny0 = (f2){(V)[2], (V)[3]};                                 \
        const f2 nz0 = (f2){(V)[4], (V)[5]};                                 \
        const f2 cw0 = (f2){(V)[6], (V)[7]};                                 \
        const f2 nx1 = (f2){(V)[8], (V)[9]};                                 \
        const f2 ny1 = (f2){(V)[10], (V)[11]};                               \
        const f2 nz1 = (f2){(V)[12], (V)[13]};                               \
        const f2 cw1 = (f2){(V)[14], (V)[15]};                               \
        f2 ra[PPT], rb[PPT];                                                 \
        quad_dist_s(nx0, ny0, nz0, cw0,                                      \
                    ZA[0], ZB[0], ZA[1], ZB[1], ZA[2], ZB[2], ZA[3], ZB[3],  \
                    ra[0], ra[1], ra[2], ra[3]);                             \
        quad_dist_s(nx0, ny0, nz0, cw0,                                      \
                    ZA[4], ZB[4], ZA[5], ZB[5], ZA[6], ZB[6], ZA[7], ZB[7],  \
                    ra[4], ra[5], ra[6], ra[7]);                             \
        quad_dist_s(nx1, ny1, nz1, cw1,                                      \
                    ZA[0], ZB[0], ZA[1], ZB[1], ZA[2], ZB[2], ZA[3], ZB[3],  \
                    rb[0], rb[1], rb[2], rb[3]);                             \
        quad_dist_s(nx1, ny1, nz1, cw1,                                      \
                    ZA[4], ZB[4], ZA[5], ZB[5], ZA[6], ZB[6], ZA[7], ZB[7],  \
                    rb[4], rb[5], rb[6], rb[7]);                             \
        const int gv = (G);                                                  \
        _Pragma("unroll")                                                    \
        for (int i = 0; i < PPT; ++i) {                                      \
            const float m1 = fminf(fminf(best[i], ra[i].x), ra[i].y);        \
            const float mn = fminf(fminf(m1, rb[i].x), rb[i].y);             \
            const bool imp = mn < best[i];                                   \
            bg[i] = imp ? gv : bg[i];                                        \
            best[i] = mn;                                                    \
        }                                                                    \
    } while (0)

    {
        f16v A1, A2, B1, B2;
        SLOAD2(A1, wbase);                                // groups 0,1
        SLOAD2(A2, wbase + 64u);
#pragma unroll 1
        for (int c = 0; c < PAIRS_PER_WAVE; c += 8) {     // 8 pairs = 4 groups
            const int g0 = wu * GROUPS_PER_WAVE + (c >> 1);
            SFENCE2(A1, A2);                              // only A1,A2 were outstanding
            SLOAD2(B1, wbase + (unsigned)(c + 4) * 32u);  // hide under 2 group-steps
            SLOAD2(B2, wbase + (unsigned)(c + 6) * 32u);
            GROUP_STEP(A1, g0);
            GROUP_STEP(A2, g0 + 1);
            SFENCE2(B1, B2);                              // only B1,B2 outstanding
            if (c + 8 < PAIRS_PER_WAVE) {
                SLOAD2(A1, wbase + (unsigned)(c + 8) * 32u);
                SLOAD2(A2, wbase + (unsigned)(c + 10) * 32u);
            }
            GROUP_STEP(B1, g0 + 2);
            GROUP_STEP(B2, g0 + 3);
        }
    }
#undef GROUP_STEP

    // Resolve the winning entry within the winning 4-entry group: recompute
    // all 4 scores with scalar chains that replicate the pk lanes BITWISE
    // (v_pk_fma lane == fmaf, v_pk_add lane == scalar add); first == best
    // -> numpy first-index within the group.
#pragma unroll
    for (int i = 0; i < PPT; ++i) {
        const int g = bg[i];
        const Pair ca = pairs[2 * g];         // per-lane gather, L1-hit (8 KB)
        const Pair cb2 = pairs[2 * g + 1];
        float s0, s1, s2, s3;
        {
#pragma clang fp contract(off)
            float m;
            m = fmaf(ca.x.x, ZA[i].x, ZB[i].y);
            m = fmaf(ca.y.x, ZA[i].y, m);
            m = fmaf(ca.z.x, ZB[i].x, m);
            s0 = m + ca.w.x;
            m = fmaf(ca.x.y, ZA[i].x, ZB[i].y);
            m = fmaf(ca.y.y, ZA[i].y, m);
            m = fmaf(ca.z.y, ZB[i].x, m);
            s1 = m + ca.w.y;
            m = fmaf(cb2.x.x, ZA[i].x, ZB[i].y);
            m = fmaf(cb2.y.x, ZA[i].y, m);
            m = fmaf(cb2.z.x, ZB[i].x, m);
            s2 = m + cb2.w.x;
            m = fmaf(cb2.x.y, ZA[i].x, ZB[i].y);
            m = fmaf(cb2.y.y, ZA[i].y, m);
            m = fmaf(cb2.z.y, ZB[i].x, m);
            s3 = m + cb2.w.y;
        }
        const int m4 = (s0 == best[i]) ? 0 : (s1 == best[i]) ? 1
                     : (s2 == best[i]) ? 2 : 3;
        cb_best[w][lane + 64 * i] = best[i];
        cb_bi[w][lane + 64 * i]   = 4 * g + m4;
    }
    __syncthreads();

    // Combine quarters (ordered strict < => numpy first-index), write, loss.
    // Thread t combines px t (= its slot w) and px t+256 (= its slot w+4):
    // reuse regs, no z re-read.
    float lsum = 0.0f;
#pragma unroll
    for (int half = 0; half < 2; ++half) {
        const int p = t + 256 * half;         // 0..511 within block
        const int slot = w + 4 * half;
        const f2 zA = ZA[slot], zB = ZB[slot];
        float bb = cb_best[0][p];
        int   kk = cb_bi[0][p];
#pragma unroll
        for (int ww = 1; ww < NWAVE; ++ww) {
            const float d  = cb_best[ww][p];
            const int   k2 = cb_bi[ww][p];
            if (d < bb) { bb = d; kk = k2; }
        }
        const int base = b * CHW + p0 + p;
        const float c0 = table[3 * kk + 0];
        const float c1 = table[3 * kk + 1];
        const float c2 = table[3 * kk + 2];
        out[base]          = c0;
        out[base + HW]     = c1;
        out[base + 2 * HW] = c2;
        const float e0 = c0 - zA.x, e1 = c1 - zA.y, e2 = c2 - zB.x;
        lsum += e0 * e0 + e1 * e1 + e2 * e2;
    }

    for (int off = 32; off > 0; off >>= 1)
        lsum += __shfl_down(lsum, off);

    if ((t & 63) == 0) wsum[w] = lsum;
    __syncthreads();
    if (t == 0) {
        const float s = wsum[0] + wsum[1] + wsum[2] + wsum[3];
        atomicAdd(loss, s * (11.0f / (float)NELEM));
    }
}

extern "C" void kernel_launch(void* const* d_in, const int* in_sizes, int n_in,
                              void* d_out, int out_size, void* d_ws, size_t ws_size,
                              hipStream_t stream)
{
    const float* z     = (const float*)d_in[0];
    const float* table = (const float*)d_in[1];
    float* out  = (float*)d_out;
    float* loss = out + NELEM;

    prep_kernel<<<1, 256, 0, stream>>>(table, loss);
    vq_kernel<<<NPIX / BLKPX, 256, 0, stream>>>(z, table, out, loss);
}